// Round 1
// 353.958 us; speedup vs baseline: 1.1235x; 1.1235x over previous
//
#include <hip/hip_runtime.h>
#include <hip/hip_bf16.h>
#include <stdint.h>
#include <stddef.h>

// SimpleStateSpaceModel: B=4, S=4096, D=1024. FP32 in/out; bf16 MFMA inside.
// Pipeline (106 MB of d_ws):
//   C0 cast_all         : x->xb (32MB), {dt_w,B_w,C_w}->wcat (6MB)
//   K1 gemm8<bf16>      : P[m,0:1024]=x@dt_w^T, P[m,1024:2048]=x@B_w^T
//   S1 scan_local       : g,u from (P,xb); in-place P <- [hl(t) | pg(t)]
//   S2 scan_carry4      : sequential combine over 128 chunks
//   S3 scan_fix         : h(t) = hl(t) + carry*pg(t)
//   K6 gemm8<f32>       : out = h@C_w^T + D*x (xb epilogue)
// R-this: GEMMs upgraded from 128²/BK32 2-barrier (m97-structure, ~660 TF here)
// to 256²/BK64 8-wave 4-phase-per-tile pipelined schedule: counted vmcnt(4)
// (never 0 in steady state), read-side XOR swizzle with pre-swizzled global
// source (linear global_load_lds dest), setprio around MFMA clusters.

#define Bdim 4
#define Sdim 4096
#define Dd   1024
#define Mdim (Bdim * Sdim)      // 16384
#define CCH  128                // scan chunks per sequence
#define LCH  (Sdim / CCH)       // 32 steps per chunk

typedef __attribute__((ext_vector_type(8))) short  short8;
typedef __attribute__((ext_vector_type(4))) short  short4v;
typedef __attribute__((ext_vector_type(4))) float  floatx4;

__device__ __forceinline__ float b2f(short v) {
  unsigned u = ((unsigned)(unsigned short)v) << 16;
  float f; __builtin_memcpy(&f, &u, 4); return f;
}
__device__ __forceinline__ short f2b(float f) {
  unsigned u; __builtin_memcpy(&u, &f, 4);
  u += 0x7fffu + ((u >> 16) & 1u);   // round-to-nearest-even
  return (short)(u >> 16);
}

__device__ __forceinline__ short8 ld8f(const float* p) {
  floatx4 lo = *(const floatx4*)p;
  floatx4 hi = *(const floatx4*)(p + 4);
  short8 r;
  r[0] = f2b(lo[0]); r[1] = f2b(lo[1]); r[2] = f2b(lo[2]); r[3] = f2b(lo[3]);
  r[4] = f2b(hi[0]); r[5] = f2b(hi[1]); r[6] = f2b(hi[2]); r[7] = f2b(hi[3]);
  return r;
}

__device__ __forceinline__ void st_out(short* p, float v) { *p = f2b(v); }
__device__ __forceinline__ void st_out(float* p, float v) { *p = v; }

// async 16B global->LDS (DMA). lds dest wave-uniform; lane i -> l + i*16. [m97]
__device__ __forceinline__ void cp16(const void* g, void* l) {
  __builtin_amdgcn_global_load_lds(
      (__attribute__((address_space(1))) void*)g,
      (__attribute__((address_space(3))) void*)l, 16, 0, 0);
}

// ---------------------------------------------------------------------------
// gemm8: Out[m,n] = sum_k A[m,k]*W[n,k], A/W bf16.
// 256x256 tile, BK=64, 8 waves (2M x 4N), per-wave 128x64 output.
// LDS 128 KiB: As[2][256][64] | Bs[2][256][64] bf16, XOR-swizzled columns.
// Per K-tile: 4 phases = C-quadrants (0,0),(0,1),(1,1),(1,0); each phase
// stages one consumption-aligned half-tile of K-tile t+1 into the other
// buffer.  A-half h = rows with bit6==h; B-half h = rows with bit5==h, so
// phase (mh,nh) reads exactly A-half mh and B-half nh.  Steady-state waits:
// vmcnt(4) at phases 1-3 (6-8 loads in flight, never drained); last tile
// drains 4->2->0.  FUSE epilogue: Out += Dp[n]*b2f(Xr[m*ldx+n]).
// ---------------------------------------------------------------------------

// staging: chunk c = tid (+512 pass1); physical LDS row r advances with c>>3;
// physical 16B slot (c&7) holds logical col ((c&7)^(r&7))*8 elems, so the
// read-side swizzle phys_col = logical ^ ((row&7)<<4) sees linear data. [m201]
#define STGA(bufB, h, kk) do { \
  cp16(Ag + (size_t)((h) * 64) * lda + (kk), \
       smc + (bufB) + ((h) * 64 + ldsArow) * 128); \
  cp16(Ag + (size_t)((h) * 64 + 128) * lda + (kk), \
       smc + (bufB) + ((h) * 64 + 128 + ldsArow) * 128); \
} while (0)

#define STGB(bufB, h, kk) do { \
  cp16(Bg + (size_t)((h) * 32) * ldw + (kk), \
       smc + (bufB) + ((h) * 32 + ldsBrow) * 128); \
  cp16(Bg + (size_t)((h) * 32 + 128) * ldw + (kk), \
       smc + (bufB) + ((h) * 32 + 128 + ldsBrow) * 128); \
} while (0)

#define LDA4(bufB, mh) do { \
  _Pragma("unroll") \
  for (int mf = 0; mf < 4; ++mf) { \
    const char* p_ = smc + (bufB) + (wm + (mh) * 64 + mf * 16 + l16) * 128; \
    a[mf][0] = *(const short8*)(p_ + c0x); \
    a[mf][1] = *(const short8*)(p_ + c1x); \
  } \
} while (0)

#define LDB2(bufB, nh, bb) do { \
  _Pragma("unroll") \
  for (int g = 0; g < 2; ++g) { \
    const char* p_ = smc + (bufB) + (wn + (nh) * 32 + g * 16 + l16) * 128; \
    bb[g][0] = *(const short8*)(p_ + c0x); \
    bb[g][1] = *(const short8*)(p_ + c1x); \
  } \
} while (0)

// 16 MFMA cluster = one C-quadrant over K=64. setprio (T5); sched_barrier(0)
// pins the cluster before the next raw s_barrier (rule #18).
#define MM8(mh, nh, bb) do { \
  __builtin_amdgcn_s_setprio(1); \
  _Pragma("unroll") \
  for (int mf = 0; mf < 4; ++mf) { \
    _Pragma("unroll") \
    for (int g = 0; g < 2; ++g) { \
      floatx4 c_ = acc[(mh) * 4 + mf][(nh) * 2 + g]; \
      c_ = __builtin_amdgcn_mfma_f32_16x16x32_bf16(a[mf][0], bb[g][0], c_, 0, 0, 0); \
      c_ = __builtin_amdgcn_mfma_f32_16x16x32_bf16(a[mf][1], bb[g][1], c_, 0, 0, 0); \
      acc[(mh) * 4 + mf][(nh) * 2 + g] = c_; \
    } \
  } \
  __builtin_amdgcn_s_setprio(0); \
  __builtin_amdgcn_sched_barrier(0); \
} while (0)

// counted-vmcnt wait + barrier in one volatile asm: no memory op (ds_read /
// global_load_lds) can cross either; all waves' prior stages landed after it.
#define WBAR(n) asm volatile("s_waitcnt vmcnt(" n ")\n\ts_barrier" ::: "memory")
#define BARO()  asm volatile("s_barrier" ::: "memory")

template <typename OT, bool FUSE>
__global__ __launch_bounds__(512, 2) void gemm8(
    const short* __restrict__ A, int lda,
    const short* __restrict__ W, int ldw,    // bf16 [N][K] row-major
    OT* __restrict__ Out, int ldo, int K,
    const float* __restrict__ Dp, const short* __restrict__ Xr, int ldx)
{
  __shared__ short smem[65536];   // 128 KiB: Abuf0|Abuf1|Bbuf0|Bbuf1, 32K each
  char* smc = (char*)smem;

  const int tid  = threadIdx.x;
  const int lane = tid & 63, wv = tid >> 6;
  const int quad = lane >> 4, l16 = lane & 15;
  const int wm = (wv & 1) << 7;           // 0 / 128
  const int wn = (wv >> 1) << 6;          // 0,64,128,192
  const int m0 = blockIdx.x << 8;
  const int n0 = blockIdx.y << 8;

  // read-side swizzle: phys col-byte = logical ^ ((row&7)<<4); row&7 == l16&7
  const int sx  = (l16 & 7) << 4;
  const int c0x = (quad << 4) ^ sx;            // ks=0 fragment column
  const int c1x = (64 + (quad << 4)) ^ sx;     // ks=1 fragment column

  // per-thread staging source bases (pre-swizzled global column)
  const int r0 = tid >> 3;                                  // 0..63
  const int sk = (((tid & 7) ^ (r0 & 7)) << 3);             // elems, <64
  const short* Ag = A + (size_t)(m0 + r0) * lda + sk;
  const short* Bg = W + (size_t)(n0 + ((r0 >> 5) << 6) + (r0 & 31)) * ldw + sk;
  const int ldsArow = wv << 3;                              // wave-uniform
  const int ldsBrow = ((wv >> 2) << 6) + ((wv << 3) & 31);  // wave-uniform

  short8 a[4][2], b0[2][2], b1[2][2];
  floatx4 acc[8][4] = {};

  // prologue: stage tile 0 into buf0, consumption order A0, B0, B1, A1
  STGA(0, 0, 0);
  STGB(65536, 0, 0);
  STGB(65536, 1, 0);
  STGA(0, 1, 0);

  const int NT = K >> 6;
  for (int t = 0; t < NT; ++t) {
    const int cb   = t & 1;
    const int ab   = cb << 15;              // compute A buffer (bytes)
    const int bbuf = 65536 + ab;            // compute B buffer
    const int an   = (cb ^ 1) << 15;        // stage A buffer
    const int bn   = 65536 + an;            // stage B buffer
    const int kk   = (t + 1) << 6;
    const bool st  = (t + 1) < NT;

    // phase 1: quadrant (0,0); needs A-h0 (staged t-1.ph1) + B-h0 (t-1.ph2)
    WBAR("4");
    LDA4(ab, 0);
    LDB2(bbuf, 0, b0);
    if (st) STGA(an, 0, kk);
    MM8(0, 0, b0);

    // phase 2: quadrant (0,1); needs B-h1 (staged t-1.ph3)
    if (st) WBAR("4"); else WBAR("2");
    LDB2(bbuf, 1, b1);
    if (st) STGB(bn, 0, kk);
    MM8(0, 1, b1);

    // phase 3: quadrant (1,1); needs A-h1 (staged t-1.ph4)
    if (st) WBAR("4"); else WBAR("0");
    LDA4(ab, 1);
    if (st) STGB(bn, 1, kk);
    MM8(1, 1, b1);

    // phase 4: quadrant (1,0); b0 still in registers, no LDS reads
    BARO();
    if (st) STGA(an, 1, kk);
    MM8(1, 0, b0);
  }

  // C/D layout: row = quad*4 + r, col = l16  [verified m89/m91]
#pragma unroll
  for (int i = 0; i < 8; ++i) {
#pragma unroll
    for (int j = 0; j < 4; ++j) {
#pragma unroll
      for (int r = 0; r < 4; ++r) {
        int m = m0 + wm + i * 16 + quad * 4 + r;
        int n = n0 + wn + j * 16 + l16;
        float v = acc[i][j][r];
        if (FUSE) v += Dp[n] * b2f(Xr[(size_t)m * ldx + n]);
        st_out(Out + (size_t)m * ldo + n, v);
      }
    }
  }
}

// ---------------------------------------------------------------------------
// C0: fused cast fp32->bf16 for x (16M elems) and the 3 weights (1M each).
// ---------------------------------------------------------------------------
__global__ __launch_bounds__(256) void cast_all(
    const float* __restrict__ x, const float* __restrict__ dt_w,
    const float* __restrict__ B_w, const float* __restrict__ C_w,
    short* __restrict__ xb, short* __restrict__ wcat)
{
  size_t i = ((size_t)blockIdx.x * 256 + threadIdx.x) * 8;
  const size_t NX = (size_t)Mdim * Dd;           // 16,777,216
  const size_t NW = (size_t)Dd * Dd;             // 1,048,576
  if (i < NX) {
    *(short8*)(xb + i) = ld8f(x + i);
  } else {
    size_t j = i - NX;
    const float* src = (j < NW) ? (dt_w + j)
                     : (j < 2 * NW) ? (B_w + (j - NW))
                                    : (C_w + (j - 2 * NW));
    *(short8*)(wcat + j) = ld8f(src);
  }
}

// ---------------------------------------------------------------------------
// Gate/input: z = dt_pre + dt_b; sp = softplus(z); g = exp(sp*-exp(A_log));
// u = sp * Bp * x.
// ---------------------------------------------------------------------------
__device__ __forceinline__ void gate_in(float dtp, float db, float nA,
                                        float bp, float xv,
                                        float& g, float& u) {
  float z  = dtp + db;
  float sp = fmaxf(z, 0.f) + log1pf(expf(-fabsf(z)));
  g = expf(sp * nA);
  u = sp * bp * xv;
}

// ---------------------------------------------------------------------------
// S1: single transcendental pass. Per (b,c) chunk, thread owns 4 d.
// ---------------------------------------------------------------------------
__global__ __launch_bounds__(256) void scan_local(
    short* __restrict__ P, const short* __restrict__ xb,
    const float* __restrict__ dt_b, const float* __restrict__ A_log,
    const float* __restrict__ h0,
    float* __restrict__ Pc, float* __restrict__ Hl)
{
  const int b  = blockIdx.x >> 7;
  const int c  = blockIdx.x & 127;
  const int d0 = threadIdx.x * 4;

  floatx4 db = *(const floatx4*)(dt_b + d0);
  floatx4 al = *(const floatx4*)(A_log + d0);
  float nA[4], p[4] = {1.f, 1.f, 1.f, 1.f}, h[4] = {};
#pragma unroll
  for (int j = 0; j < 4; j++) nA[j] = -expf(al[j]);

  const size_t mrow = (size_t)b * Sdim + (size_t)c * LCH;
  for (int t = 0; t < LCH; t++) {
    size_t m = mrow + t;
    short4v dt4 = *(const short4v*)(P + m * 2048 + d0);
    short4v bp4 = *(const short4v*)(P + m * 2048 + 1024 + d0);
    short4v xv4 = *(const short4v*)(xb + m * Dd + d0);
    short4v hl4, pg4;
#pragma unroll
    for (int j = 0; j < 4; j++) {
      float g, u;
      gate_in(b2f(dt4[j]), db[j], nA[j], b2f(bp4[j]), b2f(xv4[j]), g, u);
      if (c == 0 && t == 0) u += g * h0[b * Dd + d0 + j];
      h[j] = g * h[j] + u;
      p[j] *= g;
      hl4[j] = f2b(h[j]);
      pg4[j] = f2b(p[j]);
    }
    *(short4v*)(P + m * 2048 + d0)        = hl4;   // own addrs: safe in-place
    *(short4v*)(P + m * 2048 + 1024 + d0) = pg4;
  }
  size_t o = ((size_t)b * CCH + c) * Dd + d0;
  *(floatx4*)(Pc + o) = floatx4{p[0], p[1], p[2], p[3]};
  *(floatx4*)(Hl + o) = floatx4{h[0], h[1], h[2], h[3]};
}

// ---------------------------------------------------------------------------
// S2: sequential carry over 128 chunks; carry-in overwrites Pc.
// ---------------------------------------------------------------------------
__global__ __launch_bounds__(256) void scan_carry4(
    float* __restrict__ Pc, const float* __restrict__ Hl)
{
  const int t  = blockIdx.x * 256 + threadIdx.x;   // 0..1023
  const int b  = t >> 8;
  const int d0 = (t & 255) * 4;
  floatx4 st = {};
  for (int c = 0; c < CCH; c++) {
    size_t o = ((size_t)b * CCH + c) * Dd + d0;
    floatx4 pv = *(const floatx4*)(Pc + o);
    floatx4 hv = *(const floatx4*)(Hl + o);
    *(floatx4*)(Pc + o) = st;
    st = pv * st + hv;
  }
}

// ---------------------------------------------------------------------------
// S3: chain-free fixup: h(t) = hl(t) + carry * pg(t); h -> gate slot of P.
// ---------------------------------------------------------------------------
__global__ __launch_bounds__(256) void scan_fix(
    short* __restrict__ P, const float* __restrict__ carry)
{
  size_t idx = ((size_t)blockIdx.x * 256 + threadIdx.x) * 4;  // over 16M elems
  const int m  = (int)(idx >> 10);
  const int d0 = (int)(idx & 1023);
  const int b  = m >> 12;
  const int c  = (m & (Sdim - 1)) >> 5;      // s / LCH
  short4v hl4 = *(const short4v*)(P + (size_t)m * 2048 + d0);
  short4v pg4 = *(const short4v*)(P + (size_t)m * 2048 + 1024 + d0);
  floatx4 cv  = *(const floatx4*)(carry + ((size_t)b * CCH + c) * Dd + d0);
  short4v o4;
#pragma unroll
  for (int j = 0; j < 4; j++)
    o4[j] = f2b(b2f(hl4[j]) + cv[j] * b2f(pg4[j]));
  *(short4v*)(P + (size_t)m * 2048 + d0) = o4;
}

// ---------------------------------------------------------------------------
extern "C" void kernel_launch(void* const* d_in, const int* in_sizes, int n_in,
                              void* d_out, int out_size, void* d_ws, size_t ws_size,
                              hipStream_t stream)
{
  const float* x     = (const float*)d_in[0];  // [4,4096,1024] fp32
  const float* h0    = (const float*)d_in[1];  // [4,1024]
  const float* dt_w  = (const float*)d_in[2];  // [1024,1024]
  const float* dt_b  = (const float*)d_in[3];  // [1024]
  const float* A_log = (const float*)d_in[4];  // [1024]
  const float* B_w   = (const float*)d_in[5];  // [1024,1024]
  const float* C_w   = (const float*)d_in[6];  // [1024,1024]
  const float* Dp    = (const float*)d_in[7];  // [1024]
  float* out = (float*)d_out;                  // [4,4096,1024] fp32

  // ws layout (106 MB):
  //   [0,64)    P bf16 [16384][2048]: dt_pre|Bp -> hl|pg -> h|pg
  //   [64,96)   xb bf16 [16384][1024]
  //   [96,102)  wcat bf16 [3072][1024]  (dt_w | B_w | C_w)
  //   [102,104) Pc fp32 [4][128][1024]
  //   [104,106) Hl fp32 [4][128][1024]
  char* ws = (char*)d_ws;
  short* P    = (short*)(ws);
  short* xb   = (short*)(ws + (64ull  << 20));
  short* wcat = (short*)(ws + (96ull  << 20));
  float* Pc   = (float*)(ws + (102ull << 20));
  float* Hl   = (float*)(ws + (104ull << 20));

  // C0: all casts in one launch: (16M + 3M)/8/256 = 9728 blocks
  cast_all<<<9728, 256, 0, stream>>>(x, dt_w, B_w, C_w, xb, wcat);

  // K1: P = x @ [dt_w;B_w]^T  (M=16384, N=2048, K=1024), 256² tiles
  gemm8<short, false><<<dim3(Mdim / 256, 2048 / 256), 512, 0, stream>>>(
      xb, Dd, wcat, Dd, P, 2048, 1024, nullptr, nullptr, 0);

  // S1-S3: chunked scan, transcendentals once, fixup chain-free
  scan_local<<<Bdim * CCH, 256, 0, stream>>>(P, xb, dt_b, A_log, h0, Pc, Hl);
  scan_carry4<<<4, 256, 0, stream>>>(Pc, Hl);
  scan_fix<<<(Mdim * Dd / 4) / 256, 256, 0, stream>>>(P, Pc);

  // K6: out = h @ C_w^T + D*x  (h bf16 in P lda=2048; D*x epilogue from xb)
  gemm8<float, true><<<dim3(Mdim / 256, 1024 / 256), 512, 0, stream>>>(
      P, 2048, wcat + 2 * 1024 * 1024, Dd, out, Dd, 1024, Dp, xb, Dd);
}

// Round 2
// 287.938 us; speedup vs baseline: 1.3810x; 1.2293x over previous
//
#include <hip/hip_runtime.h>
#include <hip/hip_bf16.h>
#include <stdint.h>
#include <stddef.h>

// SimpleStateSpaceModel: B=4, S=4096, D=1024. FP32 in/out; bf16 MFMA inside.
// Pipeline (106 MB of d_ws):
//   C0 cast_all         : x->xb (32MB), {dt_w,B_w,C_w}->wcat (6MB)
//   K1 gemm8<bf16>      : P[m,0:1024]=x@dt_w^T, P[m,1024:2048]=x@B_w^T
//   S1 scan_local       : g,u from (P,xb); in-place P <- [hl(t) | pg(t)]
//   S2 scan_carry       : sequential combine over 128 chunks
//   S3 scan_fix         : h(t) = hl(t) + carry*pg(t)
//   K6 gemm8<f32>       : out = h@C_w^T + D*x (xb epilogue)
// R2: S1 re-shaped 1 d/thread (8192 waves, was 2048), exp2-based gate math
// (no libm softplus), HW bf16 cvt, 1-step prefetch. S2 widened to 64 CUs
// with 8-deep register-group prefetch. GEMMs unchanged from R1 (8-phase).

#define Bdim 4
#define Sdim 4096
#define Dd   1024
#define Mdim (Bdim * Sdim)      // 16384
#define CCH  128                // scan chunks per sequence
#define LCH  (Sdim / CCH)       // 32 steps per chunk

typedef __attribute__((ext_vector_type(8))) short  short8;
typedef __attribute__((ext_vector_type(4))) short  short4v;
typedef __attribute__((ext_vector_type(4))) float  floatx4;

#if __has_builtin(__builtin_amdgcn_exp2f)
#define EXP2(x) __builtin_amdgcn_exp2f(x)
#else
#define EXP2(x) exp2f(x)
#endif
#if __has_builtin(__builtin_amdgcn_logf)
#define LOG2(x) __builtin_amdgcn_logf(x)
#else
#define LOG2(x) __log2f(x)
#endif
#define LOG2E 1.44269504088896f
#define LN2   0.69314718055995f

__device__ __forceinline__ float b2f(short v) {
  unsigned u = ((unsigned)(unsigned short)v) << 16;
  float f; __builtin_memcpy(&f, &u, 4); return f;
}
// HW RNE bf16 convert (compiler emits v_cvt_pk_bf16_f32 / bit-ops as best)
__device__ __forceinline__ short f2b(float f) {
  __hip_bfloat16 h = __float2bfloat16(f);
  short s; __builtin_memcpy(&s, &h, 2); return s;
}

__device__ __forceinline__ short8 ld8f(const float* p) {
  floatx4 lo = *(const floatx4*)p;
  floatx4 hi = *(const floatx4*)(p + 4);
  short8 r;
  r[0] = f2b(lo[0]); r[1] = f2b(lo[1]); r[2] = f2b(lo[2]); r[3] = f2b(lo[3]);
  r[4] = f2b(hi[0]); r[5] = f2b(hi[1]); r[6] = f2b(hi[2]); r[7] = f2b(hi[3]);
  return r;
}

__device__ __forceinline__ void st_out(short* p, float v) { *p = f2b(v); }
__device__ __forceinline__ void st_out(float* p, float v) { *p = v; }

// async 16B global->LDS (DMA). lds dest wave-uniform; lane i -> l + i*16. [m97]
__device__ __forceinline__ void cp16(const void* g, void* l) {
  __builtin_amdgcn_global_load_lds(
      (__attribute__((address_space(1))) void*)g,
      (__attribute__((address_space(3))) void*)l, 16, 0, 0);
}

// ---------------------------------------------------------------------------
// gemm8: Out[m,n] = sum_k A[m,k]*W[n,k], A/W bf16.  [R1-verified]
// 256x256 tile, BK=64, 8 waves (2M x 4N), per-wave 128x64 output.
// 4 phases per K-tile = C-quadrants; counted vmcnt(4), read-side XOR swizzle
// with pre-swizzled global source, setprio around MFMA clusters.
// ---------------------------------------------------------------------------
#define STGA(bufB, h, kk) do { \
  cp16(Ag + (size_t)((h) * 64) * lda + (kk), \
       smc + (bufB) + ((h) * 64 + ldsArow) * 128); \
  cp16(Ag + (size_t)((h) * 64 + 128) * lda + (kk), \
       smc + (bufB) + ((h) * 64 + 128 + ldsArow) * 128); \
} while (0)

#define STGB(bufB, h, kk) do { \
  cp16(Bg + (size_t)((h) * 32) * ldw + (kk), \
       smc + (bufB) + ((h) * 32 + ldsBrow) * 128); \
  cp16(Bg + (size_t)((h) * 32 + 128) * ldw + (kk), \
       smc + (bufB) + ((h) * 32 + 128 + ldsBrow) * 128); \
} while (0)

#define LDA4(bufB, mh) do { \
  _Pragma("unroll") \
  for (int mf = 0; mf < 4; ++mf) { \
    const char* p_ = smc + (bufB) + (wm + (mh) * 64 + mf * 16 + l16) * 128; \
    a[mf][0] = *(const short8*)(p_ + c0x); \
    a[mf][1] = *(const short8*)(p_ + c1x); \
  } \
} while (0)

#define LDB2(bufB, nh, bb) do { \
  _Pragma("unroll") \
  for (int g = 0; g < 2; ++g) { \
    const char* p_ = smc + (bufB) + (wn + (nh) * 32 + g * 16 + l16) * 128; \
    bb[g][0] = *(const short8*)(p_ + c0x); \
    bb[g][1] = *(const short8*)(p_ + c1x); \
  } \
} while (0)

#define MM8(mh, nh, bb) do { \
  __builtin_amdgcn_s_setprio(1); \
  _Pragma("unroll") \
  for (int mf = 0; mf < 4; ++mf) { \
    _Pragma("unroll") \
    for (int g = 0; g < 2; ++g) { \
      floatx4 c_ = acc[(mh) * 4 + mf][(nh) * 2 + g]; \
      c_ = __builtin_amdgcn_mfma_f32_16x16x32_bf16(a[mf][0], bb[g][0], c_, 0, 0, 0); \
      c_ = __builtin_amdgcn_mfma_f32_16x16x32_bf16(a[mf][1], bb[g][1], c_, 0, 0, 0); \
      acc[(mh) * 4 + mf][(nh) * 2 + g] = c_; \
    } \
  } \
  __builtin_amdgcn_s_setprio(0); \
  __builtin_amdgcn_sched_barrier(0); \
} while (0)

#define WBAR(n) asm volatile("s_waitcnt vmcnt(" n ")\n\ts_barrier" ::: "memory")
#define BARO()  asm volatile("s_barrier" ::: "memory")

template <typename OT, bool FUSE>
__global__ __launch_bounds__(512, 2) void gemm8(
    const short* __restrict__ A, int lda,
    const short* __restrict__ W, int ldw,    // bf16 [N][K] row-major
    OT* __restrict__ Out, int ldo, int K,
    const float* __restrict__ Dp, const short* __restrict__ Xr, int ldx)
{
  __shared__ short smem[65536];   // 128 KiB: Abuf0|Abuf1|Bbuf0|Bbuf1, 32K each
  char* smc = (char*)smem;

  const int tid  = threadIdx.x;
  const int lane = tid & 63, wv = tid >> 6;
  const int quad = lane >> 4, l16 = lane & 15;
  const int wm = (wv & 1) << 7;           // 0 / 128
  const int wn = (wv >> 1) << 6;          // 0,64,128,192
  const int m0 = blockIdx.x << 8;
  const int n0 = blockIdx.y << 8;

  const int sx  = (l16 & 7) << 4;
  const int c0x = (quad << 4) ^ sx;            // ks=0 fragment column
  const int c1x = (64 + (quad << 4)) ^ sx;     // ks=1 fragment column

  const int r0 = tid >> 3;                                  // 0..63
  const int sk = (((tid & 7) ^ (r0 & 7)) << 3);             // elems, <64
  const short* Ag = A + (size_t)(m0 + r0) * lda + sk;
  const short* Bg = W + (size_t)(n0 + ((r0 >> 5) << 6) + (r0 & 31)) * ldw + sk;
  const int ldsArow = wv << 3;                              // wave-uniform
  const int ldsBrow = ((wv >> 2) << 6) + ((wv << 3) & 31);  // wave-uniform

  short8 a[4][2], b0[2][2], b1[2][2];
  floatx4 acc[8][4] = {};

  // prologue: stage tile 0 into buf0, consumption order A0, B0, B1, A1
  STGA(0, 0, 0);
  STGB(65536, 0, 0);
  STGB(65536, 1, 0);
  STGA(0, 1, 0);

  const int NT = K >> 6;
  for (int t = 0; t < NT; ++t) {
    const int cb   = t & 1;
    const int ab   = cb << 15;
    const int bbuf = 65536 + ab;
    const int an   = (cb ^ 1) << 15;
    const int bn   = 65536 + an;
    const int kk   = (t + 1) << 6;
    const bool st  = (t + 1) < NT;

    WBAR("4");
    LDA4(ab, 0);
    LDB2(bbuf, 0, b0);
    if (st) STGA(an, 0, kk);
    MM8(0, 0, b0);

    if (st) WBAR("4"); else WBAR("2");
    LDB2(bbuf, 1, b1);
    if (st) STGB(bn, 0, kk);
    MM8(0, 1, b1);

    if (st) WBAR("4"); else WBAR("0");
    LDA4(ab, 1);
    if (st) STGB(bn, 1, kk);
    MM8(1, 1, b1);

    BARO();
    if (st) STGA(an, 1, kk);
    MM8(1, 0, b0);
  }

  // C/D layout: row = quad*4 + r, col = l16  [verified m89/m91]
#pragma unroll
  for (int i = 0; i < 8; ++i) {
#pragma unroll
    for (int j = 0; j < 4; ++j) {
#pragma unroll
      for (int r = 0; r < 4; ++r) {
        int m = m0 + wm + i * 16 + quad * 4 + r;
        int n = n0 + wn + j * 16 + l16;
        float v = acc[i][j][r];
        if (FUSE) v += Dp[n] * b2f(Xr[(size_t)m * ldx + n]);
        st_out(Out + (size_t)m * ldo + n, v);
      }
    }
  }
}

// ---------------------------------------------------------------------------
// C0: fused cast fp32->bf16 for x (16M elems) and the 3 weights (1M each).
// ---------------------------------------------------------------------------
__global__ __launch_bounds__(256) void cast_all(
    const float* __restrict__ x, const float* __restrict__ dt_w,
    const float* __restrict__ B_w, const float* __restrict__ C_w,
    short* __restrict__ xb, short* __restrict__ wcat)
{
  size_t i = ((size_t)blockIdx.x * 256 + threadIdx.x) * 8;
  const size_t NX = (size_t)Mdim * Dd;           // 16,777,216
  const size_t NW = (size_t)Dd * Dd;             // 1,048,576
  if (i < NX) {
    *(short8*)(xb + i) = ld8f(x + i);
  } else {
    size_t j = i - NX;
    const float* src = (j < NW) ? (dt_w + j)
                     : (j < 2 * NW) ? (B_w + (j - NW))
                                    : (C_w + (j - 2 * NW));
    *(short8*)(wcat + j) = ld8f(src);
  }
}

// ---------------------------------------------------------------------------
// S1: single transcendental pass, 1 d per thread (8192 waves).
// Gate math: z = dt_pre + dt_b; e = 2^(z*log2e); L = log2(1+e);
//   sp = ln2*L (softplus); g = 2^(nA*L)  [= exp(sp*nA)]; u = sp*Bp*x.
// In-place over P: dt slot <- hl(t), Bp slot <- pg(t); fp32 running in regs.
// ---------------------------------------------------------------------------
__global__ __launch_bounds__(256) void scan_local(
    short* __restrict__ P, const short* __restrict__ xb,
    const float* __restrict__ dt_b, const float* __restrict__ A_log,
    const float* __restrict__ h0,
    float* __restrict__ Pc, float* __restrict__ Hl)
{
  const int b = blockIdx.x >> 7;
  const int c = blockIdx.x & 127;
  const int d = blockIdx.y * 256 + threadIdx.x;

  const float db = dt_b[d];
  const float nA = -EXP2(A_log[d] * LOG2E);

  const size_t mrow = (size_t)b * Sdim + (size_t)c * LCH;
  short* pp = P + mrow * 2048 + d;           // dt slot; +1024 = Bp slot
  const short* px = xb + mrow * 1024 + d;

  float p = 1.f, h = 0.f;
  short dt_c = pp[0], bp_c = pp[1024], xv_c = px[0];
  for (int t = 0; t < LCH; ++t) {
    short dt_n = 0, bp_n = 0, xv_n = 0;
    if (t + 1 < LCH) {                       // prefetch above the serial chain
      dt_n = pp[2048]; bp_n = pp[2048 + 1024]; xv_n = px[1024];
    }
    float z  = b2f(dt_c) + db;
    float e  = EXP2(z * LOG2E);
    float L  = LOG2(1.f + e);
    float sp = LN2 * L;
    float g  = EXP2(nA * L);
    float u  = sp * b2f(bp_c) * b2f(xv_c);
    if (c == 0 && t == 0) u += g * h0[b * Dd + d];
    h = g * h + u;
    p *= g;
    pp[0]    = f2b(h);                       // own addrs: safe in-place
    pp[1024] = f2b(p);
    pp += 2048; px += 1024;
    dt_c = dt_n; bp_c = bp_n; xv_c = xv_n;
  }
  size_t o = ((size_t)b * CCH + c) * Dd + d;
  Pc[o] = p;
  Hl[o] = h;
}

// ---------------------------------------------------------------------------
// S2: sequential carry over 128 chunks; carry-in overwrites Pc.
// 64 blocks x 64 threads (scalar d-lanes, 64 CUs); 8-deep group prefetch
// so the 128-long chain pays load latency 16x, not 128x.
// ---------------------------------------------------------------------------
__global__ __launch_bounds__(64) void scan_carry(
    float* __restrict__ Pc, const float* __restrict__ Hl)
{
  const int t = blockIdx.x * 64 + threadIdx.x;   // 0..4095
  const int b = t >> 10;
  const int d = t & 1023;
  const size_t base = (size_t)b * CCH * Dd + d;
  float st = 0.f;
  for (int cg = 0; cg < CCH; cg += 8) {
    float pv[8], hv[8];
#pragma unroll
    for (int j = 0; j < 8; ++j) {
      size_t o = base + (size_t)(cg + j) * Dd;
      pv[j] = Pc[o]; hv[j] = Hl[o];
    }
#pragma unroll
    for (int j = 0; j < 8; ++j) {
      size_t o = base + (size_t)(cg + j) * Dd;
      Pc[o] = st;
      st = pv[j] * st + hv[j];
    }
  }
}

// ---------------------------------------------------------------------------
// S3: chain-free fixup: h(t) = hl(t) + carry * pg(t); h -> gate slot of P.
// ---------------------------------------------------------------------------
__global__ __launch_bounds__(256) void scan_fix(
    short* __restrict__ P, const float* __restrict__ carry)
{
  size_t idx = ((size_t)blockIdx.x * 256 + threadIdx.x) * 4;  // over 16M elems
  const int m  = (int)(idx >> 10);
  const int d0 = (int)(idx & 1023);
  const int b  = m >> 12;
  const int c  = (m & (Sdim - 1)) >> 5;      // s / LCH
  short4v hl4 = *(const short4v*)(P + (size_t)m * 2048 + d0);
  short4v pg4 = *(const short4v*)(P + (size_t)m * 2048 + 1024 + d0);
  floatx4 cv  = *(const floatx4*)(carry + ((size_t)b * CCH + c) * Dd + d0);
  short4v o4;
#pragma unroll
  for (int j = 0; j < 4; j++)
    o4[j] = f2b(b2f(hl4[j]) + cv[j] * b2f(pg4[j]));
  *(short4v*)(P + (size_t)m * 2048 + d0) = o4;
}

// ---------------------------------------------------------------------------
extern "C" void kernel_launch(void* const* d_in, const int* in_sizes, int n_in,
                              void* d_out, int out_size, void* d_ws, size_t ws_size,
                              hipStream_t stream)
{
  const float* x     = (const float*)d_in[0];  // [4,4096,1024] fp32
  const float* h0    = (const float*)d_in[1];  // [4,1024]
  const float* dt_w  = (const float*)d_in[2];  // [1024,1024]
  const float* dt_b  = (const float*)d_in[3];  // [1024]
  const float* A_log = (const float*)d_in[4];  // [1024]
  const float* B_w   = (const float*)d_in[5];  // [1024,1024]
  const float* C_w   = (const float*)d_in[6];  // [1024,1024]
  const float* Dp    = (const float*)d_in[7];  // [1024]
  float* out = (float*)d_out;                  // [4,4096,1024] fp32

  // ws layout (106 MB):
  //   [0,64)    P bf16 [16384][2048]: dt_pre|Bp -> hl|pg -> h|pg
  //   [64,96)   xb bf16 [16384][1024]
  //   [96,102)  wcat bf16 [3072][1024]  (dt_w | B_w | C_w)
  //   [102,104) Pc fp32 [4][128][1024]
  //   [104,106) Hl fp32 [4][128][1024]
  char* ws = (char*)d_ws;
  short* P    = (short*)(ws);
  short* xb   = (short*)(ws + (64ull  << 20));
  short* wcat = (short*)(ws + (96ull  << 20));
  float* Pc   = (float*)(ws + (102ull << 20));
  float* Hl   = (float*)(ws + (104ull << 20));

  // C0: all casts in one launch: (16M + 3M)/8/256 = 9728 blocks
  cast_all<<<9728, 256, 0, stream>>>(x, dt_w, B_w, C_w, xb, wcat);

  // K1: P = x @ [dt_w;B_w]^T  (M=16384, N=2048, K=1024), 256² tiles
  gemm8<short, false><<<dim3(Mdim / 256, 2048 / 256), 512, 0, stream>>>(
      xb, Dd, wcat, Dd, P, 2048, 1024, nullptr, nullptr, 0);

  // S1-S3: chunked scan, transcendentals once, fixup chain-free
  scan_local<<<dim3(Bdim * CCH, Dd / 256), 256, 0, stream>>>(
      P, xb, dt_b, A_log, h0, Pc, Hl);
  scan_carry<<<64, 64, 0, stream>>>(Pc, Hl);
  scan_fix<<<(Mdim * Dd / 4) / 256, 256, 0, stream>>>(P, Pc);

  // K6: out = h @ C_w^T + D*x  (h bf16 in P lda=2048; D*x epilogue from xb)
  gemm8<float, true><<<dim3(Mdim / 256, 1024 / 256), 512, 0, stream>>>(
      P, 2048, wcat + 2 * 1024 * 1024, Dd, out, Dd, 1024, Dp, xb, Dd);
}